// Round 9
// baseline (430.441 us; speedup 1.0000x reference)
//
#include <hip/hip_runtime.h>
#include <hip/hip_bf16.h>
#include <stdint.h>

#define NN 100000
#define NE 1600000
#define FIN 128
#define HID 64
#define COUT 16

#define BUKSH 8
#define NBUK ((NN + 255) >> BUKSH)        // 391 (scan hierarchy only)

typedef unsigned long long u64;
typedef short bf16x8 __attribute__((ext_vector_type(8)));
typedef float f32x4 __attribute__((ext_vector_type(4)));

struct Flags { int f32; int i64; };

__device__ __forceinline__ float b2f(__hip_bfloat16 v) { return __bfloat162float(v); }

__device__ __forceinline__ float ldf(const void* p, size_t i, int f32) {
    return f32 ? ((const float*)p)[i]
               : __bfloat162float(((const __hip_bfloat16*)p)[i]);
}
__device__ __forceinline__ int lde(const void* p, size_t i, int i64) {
    return i64 ? (int)((const long long*)p)[i] : ((const int*)p)[i];
}
__device__ __forceinline__ void ld4bf(const __hip_bfloat16* p, float& x0, float& x1,
                                      float& x2, float& x3) {
    union { uint2 u; __hip_bfloat16 h[4]; } v;
    v.u = *(const uint2*)p;
    x0 = b2f(v.h[0]); x1 = b2f(v.h[1]); x2 = b2f(v.h[2]); x3 = b2f(v.h[3]);
}
__device__ __forceinline__ unsigned short f2bfu(float f) {
    union { __hip_bfloat16 b; unsigned short u; } c;
    c.b = __float2bfloat16(f);          // RN
    return c.u;
}
__device__ __forceinline__ float bfu2f(unsigned short u) {
    union { unsigned short h[2]; float f; } c;
    c.h[0] = 0; c.h[1] = u;
    return c.f;
}

// ---- K0: init — dtype detect (one wave) + minkey/delpos (arrays memset'd) ----
__global__ __launch_bounds__(64) void k_init(const unsigned short* xs,
                                             const int* ei32, Flags* fl,
                                             u64* minkey, int* delpos) {
    int lane = threadIdx.x;
    int huge = 0;
    for (int i = lane * 2; i < 1024; i += 128) {
        int e = (xs[i] >> 7) & 0xFF;
        if (e >= 0xC0) huge = 1;   // fp32 low-halves have random exponents
    }
    int odd_nonzero = 0;
    for (int i = 1 + lane * 2; i < 512; i += 128) {
        if (ei32[i] != 0) odd_nonzero = 1;            // int64 high words all 0
    }
    u64 h = __ballot(huge), o = __ballot(odd_nonzero);
    if (lane == 0) {
        fl->f32 = (h != 0); fl->i64 = (o == 0);
        *minkey = ~0ull;
        *delpos = 0;
    }
}

// ---- K1: edge-parallel count — cnt/wsum per dest node + fused row==0 argmin.
// Full occupancy (6250 blocks); ~16 atomics/address over 1.2MB -> no hotspots.
// wsum fixed-point u64: exact, order-independent (deg deterministic). ----
__global__ __launch_bounds__(256) void k_count(const void* __restrict__ ei,
                                               const void* __restrict__ ew,
                                               const Flags* __restrict__ fl,
                                               int* __restrict__ cnt,
                                               u64* __restrict__ wsum,
                                               u64* __restrict__ minkey) {
    int e = blockIdx.x * 256 + threadIdx.x;
    if (e >= NE) return;
    int i64 = fl->i64, f32 = fl->f32;
    int c = lde(ei, (size_t)NE + e, i64);
    float w = ldf(ew, e, f32);
    atomicAdd(&cnt[c], 1);
    atomicAdd(&wsum[c], (u64)((double)w * 4294967296.0));
    int r = lde(ei, e, i64);
    if (r == 0) {   // fused argmin over source-0 edges (rare: ~NE/NN hits)
        u64 key = ((u64)__float_as_uint(w) << 32) | (unsigned)e;  // w>=0 monotone
        atomicMin(minkey, key);
    }
}

// ---- K2: scan level 1 — per-256-node bucket sums ----
__global__ __launch_bounds__(256) void k_s1(const int* __restrict__ cnt,
                                            int* __restrict__ bsum) {
    __shared__ int sm[256];
    int b = blockIdx.x, t = threadIdx.x;
    int node = (b << 8) + t;
    sm[t] = (node < NN) ? cnt[node] : 0;
    __syncthreads();
    for (int off = 128; off > 0; off >>= 1) {
        if (t < off) sm[t] += sm[t + off];
        __syncthreads();
    }
    if (t == 0) bsum[b] = sm[0];
}

// ---- K3: scan level 2 — rowptr = bucket base + in-bucket prefix; fused dinv ----
__global__ __launch_bounds__(256) void k_s2(const int* __restrict__ cnt,
                                            const int* __restrict__ bsum,
                                            const u64* __restrict__ wsum,
                                            const void* __restrict__ ei,
                                            const void* __restrict__ ew,
                                            const Flags* __restrict__ fl,
                                            const u64* __restrict__ minkey,
                                            int* __restrict__ rowptrN,
                                            float* __restrict__ dinv1,
                                            float* __restrict__ dinv2) {
    __shared__ int pfx[256];
    int b = blockIdx.x, t = threadIdx.x;
    // bucket base: sum of bsum[i<b] (1.5KB, L2-hot, redundant per block)
    int partial = 0;
    for (int i = t; i < NBUK; i += 256)
        if (i < b) partial += bsum[i];
    pfx[t] = partial;
    __syncthreads();
    for (int off = 128; off > 0; off >>= 1) {
        if (t < off) pfx[t] += pfx[t + off];
        __syncthreads();
    }
    int gbase = pfx[0];
    __syncthreads();
    int node = (b << 8) + t;
    int v = (node < NN) ? cnt[node] : 0;
    pfx[t] = v;
    for (int off = 1; off < 256; off <<= 1) {
        __syncthreads();
        int add = (t >= off) ? pfx[t - off] : 0;
        __syncthreads();
        pfx[t] += add;
    }
    __syncthreads();
    int excl = pfx[t] - v;
    if (node < NN) {
        rowptrN[node] = gbase + excl;
        float degv = (float)((double)wsum[node] * (1.0 / 4294967296.0));
        u64 kk = *minkey;
        int eidx = (kk == ~0ull) ? 0 : (int)(kk & 0xffffffffu);  // argmin(all-inf)==0
        int cmin = lde(ei, (size_t)NE + eidx, fl->i64);
        float wmin = ldf(ew, eidx, fl->f32);
        float d1 = degv + 1.0f;                 // +1 for self loop
        float d2 = d1 - ((node == cmin) ? wmin : 0.0f);
        dinv1[node] = rsqrtf(d1);
        dinv2[node] = rsqrtf(d2);
    }
    if (b == NBUK - 1 && t == 255) rowptrN[NN] = gbase + pfx[255];   // == NE
}

// ---- K4: edge-parallel placement into CSR. Exact delete-edge identity:
// the thread owning edge eidx records its slot. Full occupancy. ----
__global__ __launch_bounds__(256) void k_place(const void* __restrict__ ei,
                                               const void* __restrict__ ew,
                                               const Flags* __restrict__ fl,
                                               const int* __restrict__ rowptrN,
                                               int* __restrict__ cursor,
                                               const u64* __restrict__ minkey,
                                               int2* __restrict__ epack,
                                               int* __restrict__ delpos) {
    int e = blockIdx.x * 256 + threadIdx.x;
    if (e >= NE) return;
    int i64 = fl->i64, f32 = fl->f32;
    int c = lde(ei, (size_t)NE + e, i64);
    int r = lde(ei, e, i64);
    float w = ldf(ew, e, f32);
    int pos = rowptrN[c] + atomicAdd(&cursor[c], 1);
    int2 ev; ev.x = r; ev.y = __float_as_int(w);
    epack[pos] = ev;
    u64 kk = *minkey;
    int eidx = (kk == ~0ull) ? 0 : (int)(kk & 0xffffffffu);
    if (e == eidx) *delpos = pos;
}

// ---- K6: gemm1, unified. fp32 path = split-bf16 MFMA (x=x_hi+x_lo etc,
// dropped lo@lo term ~2^-18 rel); bf16 path = direct MFMA. Both pre-scale
// rows by dinv1. Uniform branch on fl->f32; one 32KB LDS buffer aliased. ----
__global__ __launch_bounds__(256, 3) void k_gemm1(const void* __restrict__ xv_,
                                                  const void* __restrict__ W1_,
                                                  const Flags* __restrict__ fl,
                                                  const float* __restrict__ dinv1,
                                                  __hip_bfloat16* __restrict__ h1) {
    __shared__ __align__(16) unsigned short Wbuf[16384];   // 32 KB
    int t = threadIdx.x;
    int wave = t >> 6, lane = t & 63;
    int quad = lane >> 4, col = lane & 15;
    if (fl->f32) {
        const float* x  = (const float*)xv_;
        const float* W1 = (const float*)W1_;
        unsigned short* Whi = Wbuf;
        unsigned short* Wlo = Wbuf + 8192;
        // stage W1 (fp32) as hi/lo bf16 in MFMA-B swizzled layout
        for (int i = t; i < 8192; i += 256) {
            int k = i >> 6;
            int n = i & 63;
            int kc = k >> 5, kr = k & 31;
            int q = kr >> 3, j = kr & 7;
            int n0 = n >> 4, c2 = n & 15;
            float w = W1[i];
            unsigned short hi = f2bfu(w);
            unsigned short lo = f2bfu(w - bfu2f(hi));
            int idx = ((n0 << 4) + (kc << 2) + q) * 128 + c2 * 8 + j;
            Whi[idx] = hi;
            Wlo[idx] = lo;
        }
        __syncthreads();
        bf16x8 Bh[4][4];             // W_hi fragments hoisted; W_lo re-read from LDS
#pragma unroll
        for (int n0 = 0; n0 < 4; ++n0)
#pragma unroll
            for (int kc = 0; kc < 4; ++kc)
                Bh[kc][n0] = *(const bf16x8*)&Whi[((n0 << 4) + (kc << 2) + quad) * 128 + col * 8];
        int tile0 = (blockIdx.x * 4 + wave) * 2;     // 2 node-tiles per wave
#pragma unroll 1
        for (int i = 0; i < 2; ++i) {
            int node0 = (tile0 + i) * 16;
            if (node0 >= NN) return;
            const float* xp = x + (size_t)(node0 + col) * FIN + quad * 8;
            float4 xv[8];
#pragma unroll
            for (int kc = 0; kc < 4; ++kc) {         // issue all 8 x-loads up front
                xv[2 * kc]     = *(const float4*)(xp + kc * 32);
                xv[2 * kc + 1] = *(const float4*)(xp + kc * 32 + 4);
            }
            f32x4 a0 = {0.f, 0.f, 0.f, 0.f}, a1 = a0, a2 = a0, a3 = a0;
#pragma unroll
            for (int kc = 0; kc < 4; ++kc) {
                float fv[8];
                fv[0] = xv[2 * kc].x;     fv[1] = xv[2 * kc].y;
                fv[2] = xv[2 * kc].z;     fv[3] = xv[2 * kc].w;
                fv[4] = xv[2 * kc + 1].x; fv[5] = xv[2 * kc + 1].y;
                fv[6] = xv[2 * kc + 1].z; fv[7] = xv[2 * kc + 1].w;
                bf16x8 Ah, Al;
#pragma unroll
                for (int j = 0; j < 8; ++j) {
                    unsigned short hi = f2bfu(fv[j]);
                    Ah[j] = (short)hi;
                    Al[j] = (short)f2bfu(fv[j] - bfu2f(hi));
                }
                int lbase = ((kc << 2) + quad) * 128 + col * 8;
                bf16x8 Bl0 = *(const bf16x8*)&Wlo[lbase];
                bf16x8 Bl1 = *(const bf16x8*)&Wlo[(1 << 4) * 128 + lbase];
                bf16x8 Bl2 = *(const bf16x8*)&Wlo[(2 << 4) * 128 + lbase];
                bf16x8 Bl3 = *(const bf16x8*)&Wlo[(3 << 4) * 128 + lbase];
                a0 = __builtin_amdgcn_mfma_f32_16x16x32_bf16(Ah, Bh[kc][0], a0, 0, 0, 0);
                a0 = __builtin_amdgcn_mfma_f32_16x16x32_bf16(Al, Bh[kc][0], a0, 0, 0, 0);
                a0 = __builtin_amdgcn_mfma_f32_16x16x32_bf16(Ah, Bl0,      a0, 0, 0, 0);
                a1 = __builtin_amdgcn_mfma_f32_16x16x32_bf16(Ah, Bh[kc][1], a1, 0, 0, 0);
                a1 = __builtin_amdgcn_mfma_f32_16x16x32_bf16(Al, Bh[kc][1], a1, 0, 0, 0);
                a1 = __builtin_amdgcn_mfma_f32_16x16x32_bf16(Ah, Bl1,      a1, 0, 0, 0);
                a2 = __builtin_amdgcn_mfma_f32_16x16x32_bf16(Ah, Bh[kc][2], a2, 0, 0, 0);
                a2 = __builtin_amdgcn_mfma_f32_16x16x32_bf16(Al, Bh[kc][2], a2, 0, 0, 0);
                a2 = __builtin_amdgcn_mfma_f32_16x16x32_bf16(Ah, Bl2,      a2, 0, 0, 0);
                a3 = __builtin_amdgcn_mfma_f32_16x16x32_bf16(Ah, Bh[kc][3], a3, 0, 0, 0);
                a3 = __builtin_amdgcn_mfma_f32_16x16x32_bf16(Al, Bh[kc][3], a3, 0, 0, 0);
                a3 = __builtin_amdgcn_mfma_f32_16x16x32_bf16(Ah, Bl3,      a3, 0, 0, 0);
            }
            __hip_bfloat16* hp = h1 + (size_t)(node0 + quad * 4) * HID + col;
#pragma unroll
            for (int r = 0; r < 4; ++r) {
                float dsc = dinv1[node0 + quad * 4 + r];
                hp[(size_t)r * HID + 0]  = __float2bfloat16(a0[r] * dsc);
                hp[(size_t)r * HID + 16] = __float2bfloat16(a1[r] * dsc);
                hp[(size_t)r * HID + 32] = __float2bfloat16(a2[r] * dsc);
                hp[(size_t)r * HID + 48] = __float2bfloat16(a3[r] * dsc);
            }
        }
    } else {
        const __hip_bfloat16* x = (const __hip_bfloat16*)xv_;
        const unsigned short* W1 = (const unsigned short*)W1_;
        unsigned short* Wf = Wbuf;
        for (int i = t; i < 8192; i += 256) {
            int k = i >> 6;
            int n = i & 63;
            int kc = k >> 5, kr = k & 31;
            int q = kr >> 3, j = kr & 7;
            int n0 = n >> 4, c2 = n & 15;
            Wf[((((n0 << 2) | kc) << 2) | q) * 128 + c2 * 8 + j] = W1[i];
        }
        __syncthreads();
        bf16x8 B[4][4];
#pragma unroll
        for (int n0 = 0; n0 < 4; ++n0)
#pragma unroll
            for (int kc = 0; kc < 4; ++kc)
                B[kc][n0] = *(const bf16x8*)&Wf[((((n0 << 2) | kc) << 2) | quad) * 128 + col * 8];
        int tile0 = (blockIdx.x * 4 + wave) * 2;
#pragma unroll 1
        for (int i = 0; i < 2; ++i) {
            int node0 = (tile0 + i) * 16;
            if (node0 >= NN) return;
            const __hip_bfloat16* xp = x + (size_t)(node0 + col) * FIN + quad * 8;
            f32x4 a0 = {0.f, 0.f, 0.f, 0.f}, a1 = a0, a2 = a0, a3 = a0;
#pragma unroll
            for (int kc = 0; kc < 4; ++kc) {
                bf16x8 A = *(const bf16x8*)(xp + kc * 32);
                a0 = __builtin_amdgcn_mfma_f32_16x16x32_bf16(A, B[kc][0], a0, 0, 0, 0);
                a1 = __builtin_amdgcn_mfma_f32_16x16x32_bf16(A, B[kc][1], a1, 0, 0, 0);
                a2 = __builtin_amdgcn_mfma_f32_16x16x32_bf16(A, B[kc][2], a2, 0, 0, 0);
                a3 = __builtin_amdgcn_mfma_f32_16x16x32_bf16(A, B[kc][3], a3, 0, 0, 0);
            }
            __hip_bfloat16* hp = h1 + (size_t)(node0 + quad * 4) * HID + col;
#pragma unroll
            for (int r = 0; r < 4; ++r) {
                float dsc = dinv1[node0 + quad * 4 + r];
                hp[(size_t)r * HID + 0]  = __float2bfloat16(a0[r] * dsc);
                hp[(size_t)r * HID + 16] = __float2bfloat16(a1[r] * dsc);
                hp[(size_t)r * HID + 32] = __float2bfloat16(a2[r] * dsc);
                hp[(size_t)r * HID + 48] = __float2bfloat16(a3[r] * dsc);
            }
        }
    }
}

// ---- K7: fused agg1 + gemm2 (16 lanes/node, batch 16 — benched geometry).
// Phase 1: out1 row = relu(dn*(sum w_e*h1s[src] + h1s[n]) + b1) parked in LDS.
// Phase 2: thread (nn,c): h2[n][c] = dinv2[n]*(row @ W2[:,c]) — k-ascending
// fp32 order, bit-identical to the standalone gemm2. ----
__global__ __launch_bounds__(256) void k_agg1(const int* __restrict__ rowptrN,
                                              const int2* __restrict__ epack,
                                              const float* __restrict__ dinv1,
                                              const __hip_bfloat16* __restrict__ h1,
                                              const void* __restrict__ b1,
                                              const void* __restrict__ W2,
                                              const Flags* __restrict__ fl,
                                              const float* __restrict__ dinv2,
                                              float* __restrict__ h2) {
    __shared__ float Ws[HID * COUT];     // 4 KB
    __shared__ float obuf[16][68];       // 16 node-rows, padded to 68 (bank spread)
    int t = threadIdx.x;
    int f32 = fl->f32;
    for (int i = t; i < HID * COUT; i += 256) Ws[i] = ldf(W2, i, f32);
    int nn = t >> 4;
    int n = blockIdx.x * 16 + nn;        // grid exact: 6250*16 == NN
    int l = t & 15;
    int f = l * 4;
    int wbase = t & 48;
    float dn = dinv1[n];
    int p0 = rowptrN[n], p1 = rowptrN[n + 1];
    float a0 = 0.f, a1 = 0.f, a2 = 0.f, a3 = 0.f;
    for (int p = p0; p < p1; p += 16) {
        int idx = p + l;
        int2 ev = make_int2(0, 0);           // pad: row 0 (safe), weight bits 0 -> c=0
        if (idx < p1) ev = epack[idx];
        float cw = __int_as_float(ev.y);
        int rj[16];
#pragma unroll
        for (int j = 0; j < 16; ++j)
            rj[j] = __shfl(ev.x, wbase + j);
        uint2 raw[16];
#pragma unroll
        for (int j = 0; j < 16; ++j)         // 16 independent 8B gathers in flight
            raw[j] = *(const uint2*)(h1 + (size_t)rj[j] * HID + f);
#pragma unroll
        for (int j = 0; j < 16; ++j) {
            float c = __shfl(cw, wbase + j);
            union { uint2 u; __hip_bfloat16 h[4]; } v; v.u = raw[j];
            a0 += c * b2f(v.h[0]);
            a1 += c * b2f(v.h[1]);
            a2 += c * b2f(v.h[2]);
            a3 += c * b2f(v.h[3]);
        }
    }
    float x0, x1, x2, x3;
    ld4bf(h1 + (size_t)n * HID + f, x0, x1, x2, x3);   // h1s[n] = dn*h1[n]
    obuf[nn][f + 0] = fmaxf(dn * (a0 + x0) + ldf(b1, f + 0, f32), 0.f);
    obuf[nn][f + 1] = fmaxf(dn * (a1 + x1) + ldf(b1, f + 1, f32), 0.f);
    obuf[nn][f + 2] = fmaxf(dn * (a2 + x2) + ldf(b1, f + 2, f32), 0.f);
    obuf[nn][f + 3] = fmaxf(dn * (a3 + x3) + ldf(b1, f + 3, f32), 0.f);
    __syncthreads();
    // fused gemm2: thread (nn, c) computes h2[n][c]
    int c = t & 15;
    const float* orow = obuf[nn];
    float acc = 0.f;
#pragma unroll 8
    for (int k = 0; k < HID; ++k)
        acc += orow[k] * Ws[k * COUT + c];
    h2[(size_t)n * COUT + c] = acc * dinv2[n];
}

// ---- K9: gather-aggregate layer 2 — batched 8-deep MLP gather ----
// h2 pre-scaled by dinv2: out = dn * (sum_e w_e * h2s[src_e] + h2s[n]) + b2
__global__ __launch_bounds__(256) void k_agg2(const int* __restrict__ rowptrN,
                                              const int2* __restrict__ epack,
                                              const float* __restrict__ dinv2,
                                              const float* __restrict__ h2,
                                              const void* __restrict__ bias2,
                                              const Flags* __restrict__ fl,
                                              const int* __restrict__ delpos,
                                              void* __restrict__ out) {
    int t = threadIdx.x;
    int n = blockIdx.x * 64 + (t >> 2);
    if (n >= NN) return;
    int l = t & 3;
    int f = l * 4;
    int wbase = t & 60;
    int f32 = fl->f32;
    int dp = *delpos;
    float dn = dinv2[n];
    int p0 = rowptrN[n], p1 = rowptrN[n + 1];
    float a0 = 0.f, a1 = 0.f, a2 = 0.f, a3 = 0.f;
    for (int p = p0; p < p1; p += 8) {
        int iA = p + l, iB = p + 4 + l;
        int2 evA = make_int2(0, 0), evB = make_int2(0, 0);
        if (iA < p1) evA = epack[iA];
        if (iB < p1) evB = epack[iB];
        float cwA = (iA == dp) ? 0.f : __int_as_float(evA.y);
        float cwB = (iB == dp) ? 0.f : __int_as_float(evB.y);
        int rj[8];
#pragma unroll
        for (int j = 0; j < 4; ++j) {
            rj[j]     = __shfl(evA.x, wbase + j);
            rj[4 + j] = __shfl(evB.x, wbase + j);
        }
        float4 hv[8];
#pragma unroll
        for (int j = 0; j < 8; ++j)          // 8 independent 16B gathers in flight
            hv[j] = *(const float4*)(h2 + (size_t)rj[j] * COUT + f);
#pragma unroll
        for (int j = 0; j < 4; ++j) {
            float cA = __shfl(cwA, wbase + j);
            float cB = __shfl(cwB, wbase + j);
            a0 += cA * hv[j].x + cB * hv[4 + j].x;
            a1 += cA * hv[j].y + cB * hv[4 + j].y;
            a2 += cA * hv[j].z + cB * hv[4 + j].z;
            a3 += cA * hv[j].w + cB * hv[4 + j].w;
        }
    }
    const float4 hn = *(const float4*)(h2 + (size_t)n * COUT + f);   // h2s[n]
    float o0 = dn * (a0 + hn.x) + ldf(bias2, f + 0, f32);
    float o1 = dn * (a1 + hn.y) + ldf(bias2, f + 1, f32);
    float o2 = dn * (a2 + hn.z) + ldf(bias2, f + 2, f32);
    float o3 = dn * (a3 + hn.w) + ldf(bias2, f + 3, f32);
    size_t idx = (size_t)n * COUT + f;
    if (f32) {
        float* op = (float*)out + idx;
        op[0] = o0; op[1] = o1; op[2] = o2; op[3] = o3;
    } else {
        union { uint2 u; __hip_bfloat16 h[4]; } pk;
        pk.h[0] = __float2bfloat16(o0); pk.h[1] = __float2bfloat16(o1);
        pk.h[2] = __float2bfloat16(o2); pk.h[3] = __float2bfloat16(o3);
        *(uint2*)((__hip_bfloat16*)out + idx) = pk.u;
    }
}

extern "C" void kernel_launch(void* const* d_in, const int* in_sizes, int n_in,
                              void* d_out, int out_size, void* d_ws, size_t ws_size,
                              hipStream_t stream) {
    const void* x  = d_in[0];
    const void* ei = d_in[1];
    const void* ew = d_in[2];
    const void* W1 = d_in[3];
    const void* b1 = d_in[4];
    const void* W2 = d_in[5];
    const void* b2 = d_in[6];

    char* wsb = (char*)d_ws;
    // zero-init group (one contiguous memset): cnt, cursor, wsum
    char* zbase = wsb;
    int*   cnt      = (int*)wsb;                       wsb += (size_t)NN * 4;
    int*   cursor   = (int*)wsb;                       wsb += (size_t)NN * 4;
    u64*   wsum     = (u64*)wsb;                       wsb += (size_t)NN * 8;
    size_t zbytes = (size_t)wsb - (size_t)zbase;
    float* dinv1    = (float*)wsb;                     wsb += (size_t)NN * 4;
    float* dinv2    = (float*)wsb;                     wsb += (size_t)NN * 4;
    int*   rowptrN  = (int*)wsb;                       wsb += (size_t)(NN + 1) * 4;
    int*   bsum     = (int*)wsb;                       wsb += (size_t)NBUK * 4;
    wsb = (char*)(((uintptr_t)wsb + 15) & ~(uintptr_t)15);
    int2*  epack    = (int2*)wsb;                      wsb += (size_t)NE * 8;
    __hip_bfloat16* h1 = (__hip_bfloat16*)wsb;         wsb += (size_t)NN * HID * 2;
    float* h2       = (float*)wsb;                     wsb += (size_t)NN * COUT * 4;
    u64*   minkey   = (u64*)wsb;                       wsb += 8;
    Flags* fl       = (Flags*)wsb;                     wsb += 8;
    int*   delpos   = (int*)wsb;                       wsb += 8;

    hipMemsetAsync(zbase, 0, zbytes, stream);
    k_init<<<1, 64, 0, stream>>>((const unsigned short*)x, (const int*)ei, fl,
                                 minkey, delpos);
    k_count<<<(NE + 255) / 256, 256, 0, stream>>>(ei, ew, fl, cnt, wsum, minkey);
    k_s1<<<NBUK, 256, 0, stream>>>(cnt, bsum);
    k_s2<<<NBUK, 256, 0, stream>>>(cnt, bsum, wsum, ei, ew, fl, minkey,
                                   rowptrN, dinv1, dinv2);
    k_place<<<(NE + 255) / 256, 256, 0, stream>>>(ei, ew, fl, rowptrN, cursor,
                                                  minkey, epack, delpos);
    k_gemm1<<<(NN / 16 + 7) / 8, 256, 0, stream>>>(x, W1, fl, dinv1, h1);
    k_agg1<<<NN / 16, 256, 0, stream>>>(rowptrN, epack, dinv1, h1, b1, W2, fl,
                                        dinv2, h2);
    k_agg2<<<(NN + 63) / 64, 256, 0, stream>>>(rowptrN, epack, dinv2, h2, b2, fl,
                                               delpos, d_out);
}

// Round 10
// 245.831 us; speedup vs baseline: 1.7510x; 1.7510x over previous
//
#include <hip/hip_runtime.h>
#include <hip/hip_bf16.h>
#include <stdint.h>

#define NN 100000
#define NE 1600000
#define FIN 128
#define HID 64
#define COUT 16

#define BUKSH 8
#define NBUK ((NN + 255) >> BUKSH)        // 391
#define PART_NB 512                       // histogram/scatter blocks
#define EPB (NE / PART_NB)                // 3125 edges per block
#define TSLCAP 5632                       // partB LDS slab (44KB; mean 4092+24sigma)

typedef unsigned long long u64;
typedef short bf16x8 __attribute__((ext_vector_type(8)));
typedef float f32x4 __attribute__((ext_vector_type(4)));

struct Flags { int f32; int i64; };

__device__ __forceinline__ float b2f(__hip_bfloat16 v) { return __bfloat162float(v); }

__device__ __forceinline__ float ldf(const void* p, size_t i, int f32) {
    return f32 ? ((const float*)p)[i]
               : __bfloat162float(((const __hip_bfloat16*)p)[i]);
}
__device__ __forceinline__ int lde(const void* p, size_t i, int i64) {
    return i64 ? (int)((const long long*)p)[i] : ((const int*)p)[i];
}
__device__ __forceinline__ void ld4bf(const __hip_bfloat16* p, float& x0, float& x1,
                                      float& x2, float& x3) {
    union { uint2 u; __hip_bfloat16 h[4]; } v;
    v.u = *(const uint2*)p;
    x0 = b2f(v.h[0]); x1 = b2f(v.h[1]); x2 = b2f(v.h[2]); x3 = b2f(v.h[3]);
}
__device__ __forceinline__ unsigned short f2bfu(float f) {
    union { __hip_bfloat16 b; unsigned short u; } c;
    c.b = __float2bfloat16(f);          // RN
    return c.u;
}
__device__ __forceinline__ float bfu2f(unsigned short u) {
    union { unsigned short h[2]; float f; } c;
    c.h[0] = 0; c.h[1] = u;
    return c.f;
}

// ---- K0: init — dtype detect (one wave) + scalars. No memsets needed:
// every array below is fully written before read. ----
__global__ __launch_bounds__(64) void k_init(const unsigned short* xs,
                                             const int* ei32, Flags* fl,
                                             u64* minkey, int* delpos,
                                             int* rowptrN) {
    int lane = threadIdx.x;
    int huge = 0;
    for (int i = lane * 2; i < 1024; i += 128) {
        int e = (xs[i] >> 7) & 0xFF;
        if (e >= 0xC0) huge = 1;   // fp32 low-halves have random exponents
    }
    int odd_nonzero = 0;
    for (int i = 1 + lane * 2; i < 512; i += 128) {
        if (ei32[i] != 0) odd_nonzero = 1;            // int64 high words all 0
    }
    u64 h = __ballot(huge), o = __ballot(odd_nonzero);
    if (lane == 0) {
        fl->f32 = (h != 0); fl->i64 = (o == 0);
        *minkey = ~0ull;
        *delpos = 0x7fffffff;
        rowptrN[NN] = NE;
    }
}

// ---- K1: per-block LDS bucket histogram -> plain stores (NO global atomics).
// Fused row==0 argmin rides the same scan. 512 blocks x 512 threads. ----
__global__ __launch_bounds__(512) void k_hist(const void* __restrict__ ei,
                                              const void* __restrict__ ew,
                                              const Flags* __restrict__ fl,
                                              int* __restrict__ blockhist,
                                              u64* __restrict__ minkey) {
    __shared__ int cnt[NBUK];
    int b = blockIdx.x, t = threadIdx.x;
    int f32 = fl->f32, i64 = fl->i64;
    for (int i = t; i < NBUK; i += 512) cnt[i] = 0;
    __syncthreads();
    int e0 = b * EPB;
    for (int i = t; i < EPB; i += 512) {
        int e = e0 + i;
        int c = lde(ei, (size_t)NE + e, i64);
        atomicAdd(&cnt[c >> BUKSH], 1);
        int r = lde(ei, (size_t)e, i64);
        if (r == 0) {   // fused argmin over source-0 edges (rare)
            float w = ldf(ew, e, f32);
            u64 key = ((u64)__float_as_uint(w) << 32) | (unsigned)e;  // w>=0 monotone
            atomicMin(minkey, key);
        }
    }
    __syncthreads();
    for (int i = t; i < NBUK; i += 512)
        blockhist[(size_t)b * NBUK + i] = cnt[i];     // coalesced, no atomics
}

// ---- K2: bucket totals (one block per bucket; reads strided but L2-shared) ----
__global__ __launch_bounds__(256) void k_scan1(const int* __restrict__ blockhist,
                                               int* __restrict__ buktotal) {
    __shared__ int sm[256];
    int i = blockIdx.x, t = threadIdx.x;
    int s = 0;
    for (int b = t; b < PART_NB; b += 256) s += blockhist[(size_t)b * NBUK + i];
    sm[t] = s;
    __syncthreads();
    for (int off = 128; off > 0; off >>= 1) {
        if (t < off) sm[t] += sm[t + off];
        __syncthreads();
    }
    if (t == 0) buktotal[i] = sm[0];
}

// ---- K3: per-bucket base + exclusive prefix over blocks -> blockbase.
// Deterministic placement; zero atomic contention. 391 blocks x 512 thr. ----
__global__ __launch_bounds__(512) void k_scan2(const int* __restrict__ blockhist,
                                               const int* __restrict__ buktotal,
                                               int* __restrict__ blockbase,
                                               int* __restrict__ bucketBaseArr) {
    __shared__ int pfx[512];
    __shared__ int bbs;
    int i = blockIdx.x, t = threadIdx.x;
    // bucket base = sum of totals of buckets < i (1.5KB, L2-hot)
    pfx[t] = (t < i && t < NBUK) ? buktotal[t] : 0;
    __syncthreads();
    for (int off = 256; off > 0; off >>= 1) {
        if (t < off) pfx[t] += pfx[t + off];
        __syncthreads();
    }
    if (t == 0) { bbs = pfx[0]; bucketBaseArr[i] = pfx[0]; }
    __syncthreads();
    int gbase = bbs;
    __syncthreads();
    // exclusive prefix over the 512 block-counts for this bucket
    int v = blockhist[(size_t)t * NBUK + i];
    pfx[t] = v;
    for (int off = 1; off < 512; off <<= 1) {
        __syncthreads();
        int add = (t >= off) ? pfx[t - off] : 0;
        __syncthreads();
        pfx[t] += add;
    }
    __syncthreads();
    blockbase[(size_t)t * NBUK + i] = gbase + pfx[t] - v;
}

// ---- K4: scatter edges into exactly-packed bucket slabs (tmp).
// pos = blockbase[b][buk] + LDS-local offset. No global atomics. ----
__global__ __launch_bounds__(512) void k_scat(const void* __restrict__ ei,
                                              const void* __restrict__ ew,
                                              const Flags* __restrict__ fl,
                                              const int* __restrict__ blockbase,
                                              long long* __restrict__ tmp) {
    __shared__ int cnt[NBUK];
    int b = blockIdx.x, t = threadIdx.x;
    int f32 = fl->f32, i64 = fl->i64;
    for (int i = t; i < NBUK; i += 512) cnt[i] = 0;
    __syncthreads();
    int e0 = b * EPB;
    const int* bb = blockbase + (size_t)b * NBUK;     // 1.5KB, L1-hot
    for (int i = t; i < EPB; i += 512) {
        int e = e0 + i;
        int c = lde(ei, (size_t)NE + e, i64);
        int r = lde(ei, (size_t)e, i64);
        float w = ldf(ew, e, f32);
        int buk = c >> BUKSH;
        int local = atomicAdd(&cnt[buk], 1);
        int pos = bb[buk] + local;
        unsigned lo = (unsigned)r | (((unsigned)c & 255u) << 17);
        tmp[pos] = ((long long)__float_as_int(w) << 32) | lo;
    }
}

// ---- K5: per-bucket CSR build. 512 threads (8 waves), slab LDS-staged with
// overflow guard. Fused: rowptr, exact fixed-point deg -> dinv1/dinv2,
// epack placement, delete-edge value-match (value-identical edges are
// interchangeable; atomicMin picks one). ----
__global__ __launch_bounds__(512) void k_partB(const int* __restrict__ buktotal,
                                               const int* __restrict__ bucketBaseArr,
                                               const long long* __restrict__ tmp,
                                               int2* __restrict__ epack,
                                               int* __restrict__ rowptrN,
                                               const void* __restrict__ ei,
                                               const void* __restrict__ ew,
                                               const Flags* __restrict__ fl,
                                               const u64* __restrict__ minkey,
                                               float* __restrict__ dinv1,
                                               float* __restrict__ dinv2,
                                               int* __restrict__ delpos) {
    __shared__ long long tsl[TSLCAP];    // 44KB
    __shared__ int cnt[256];
    __shared__ int pfx[256];
    __shared__ u64 wsum[256];
    int b = blockIdx.x, t = threadIdx.x;
    int count = buktotal[b];
    int gbase = bucketBaseArr[b];
    const long long* ts = tmp + gbase;   // slab exactly [gbase, gbase+count)
    int stage = count < TSLCAP ? count : TSLCAP;
    for (int i = t; i < stage; i += 512) tsl[i] = ts[i];
    if (t < 256) { cnt[t] = 0; wsum[t] = 0; }
    __syncthreads();
    for (int i = t; i < count; i += 512) {
        long long pk = (i < TSLCAP) ? tsl[i] : ts[i];
        unsigned lo = (unsigned)pk;
        int nl = (int)((lo >> 17) & 255u);
        atomicAdd(&cnt[nl], 1);
        float w = __int_as_float((int)(pk >> 32));
        // w in [0,1]: w*2^32 exact in double — deg deterministic/exact
        atomicAdd(&wsum[nl], (u64)((double)w * 4294967296.0));
    }
    __syncthreads();
    int v = 0;
    if (t < 256) { v = cnt[t]; pfx[t] = v; }
    for (int off = 1; off < 256; off <<= 1) {
        __syncthreads();
        int add = (t < 256 && t >= off) ? pfx[t - off] : 0;
        __syncthreads();
        if (t < 256) pfx[t] += add;
    }
    __syncthreads();
    // deleted-edge identity (L2-hot scalars, all threads)
    u64 kk = *minkey;
    int eidx = (kk == ~0ull) ? 0 : (int)(kk & 0xffffffffu);  // argmin(all-inf)==0
    int smin  = lde(ei, (size_t)eidx, fl->i64);
    int cmin  = lde(ei, (size_t)NE + eidx, fl->i64);
    int wminb = __float_as_int(ldf(ew, eidx, fl->f32));
    bool myb = (b == (cmin >> BUKSH));
    int clow = cmin & 255;
    if (t < 256) {
        int excl = pfx[t] - v;
        int node = (b << BUKSH) + t;
        if (node < NN) {
            rowptrN[node] = gbase + excl;
            float degv = (float)((double)wsum[t] * (1.0 / 4294967296.0));
            float d1 = degv + 1.0f;                 // +1 for self loop
            float d2 = d1 - ((node == cmin) ? __int_as_float(wminb) : 0.0f);
            dinv1[node] = rsqrtf(d1);
            dinv2[node] = rsqrtf(d2);
        }
        cnt[t] = gbase + excl;       // reuse as write cursor
    }
    __syncthreads();
    for (int i = t; i < count; i += 512) {
        long long pk = (i < TSLCAP) ? tsl[i] : ts[i];
        unsigned lo = (unsigned)pk;
        int nl = (int)((lo >> 17) & 255u);
        int pos = atomicAdd(&cnt[nl], 1);
        long long outpk = (pk & 0xFFFFFFFF00000000LL) | (lo & 0x1FFFFu);  // .x=src .y=w
        *(long long*)(epack + pos) = outpk;
        if (myb && nl == clow && (int)(lo & 0x1FFFFu) == smin
            && (int)(pk >> 32) == wminb)
            atomicMin(delpos, pos);
    }
}

// ---- K6: gemm1, unified. fp32 path = split-bf16 MFMA (x=x_hi+x_lo etc,
// dropped lo@lo term ~2^-18 rel); bf16 path = direct MFMA. Both pre-scale
// rows by dinv1. ----
__global__ __launch_bounds__(256, 3) void k_gemm1(const void* __restrict__ xv_,
                                                  const void* __restrict__ W1_,
                                                  const Flags* __restrict__ fl,
                                                  const float* __restrict__ dinv1,
                                                  __hip_bfloat16* __restrict__ h1) {
    __shared__ __align__(16) unsigned short Wbuf[16384];   // 32 KB
    int t = threadIdx.x;
    int wave = t >> 6, lane = t & 63;
    int quad = lane >> 4, col = lane & 15;
    if (fl->f32) {
        const float* x  = (const float*)xv_;
        const float* W1 = (const float*)W1_;
        unsigned short* Whi = Wbuf;
        unsigned short* Wlo = Wbuf + 8192;
        for (int i = t; i < 8192; i += 256) {
            int k = i >> 6;
            int n = i & 63;
            int kc = k >> 5, kr = k & 31;
            int q = kr >> 3, j = kr & 7;
            int n0 = n >> 4, c2 = n & 15;
            float w = W1[i];
            unsigned short hi = f2bfu(w);
            unsigned short lo = f2bfu(w - bfu2f(hi));
            int idx = ((n0 << 4) + (kc << 2) + q) * 128 + c2 * 8 + j;
            Whi[idx] = hi;
            Wlo[idx] = lo;
        }
        __syncthreads();
        bf16x8 Bh[4][4];
#pragma unroll
        for (int n0 = 0; n0 < 4; ++n0)
#pragma unroll
            for (int kc = 0; kc < 4; ++kc)
                Bh[kc][n0] = *(const bf16x8*)&Whi[((n0 << 4) + (kc << 2) + quad) * 128 + col * 8];
        int tile0 = (blockIdx.x * 4 + wave) * 2;
#pragma unroll 1
        for (int i = 0; i < 2; ++i) {
            int node0 = (tile0 + i) * 16;
            if (node0 >= NN) return;
            const float* xp = x + (size_t)(node0 + col) * FIN + quad * 8;
            float4 xv[8];
#pragma unroll
            for (int kc = 0; kc < 4; ++kc) {
                xv[2 * kc]     = *(const float4*)(xp + kc * 32);
                xv[2 * kc + 1] = *(const float4*)(xp + kc * 32 + 4);
            }
            f32x4 a0 = {0.f, 0.f, 0.f, 0.f}, a1 = a0, a2 = a0, a3 = a0;
#pragma unroll
            for (int kc = 0; kc < 4; ++kc) {
                float fv[8];
                fv[0] = xv[2 * kc].x;     fv[1] = xv[2 * kc].y;
                fv[2] = xv[2 * kc].z;     fv[3] = xv[2 * kc].w;
                fv[4] = xv[2 * kc + 1].x; fv[5] = xv[2 * kc + 1].y;
                fv[6] = xv[2 * kc + 1].z; fv[7] = xv[2 * kc + 1].w;
                bf16x8 Ah, Al;
#pragma unroll
                for (int j = 0; j < 8; ++j) {
                    unsigned short hi = f2bfu(fv[j]);
                    Ah[j] = (short)hi;
                    Al[j] = (short)f2bfu(fv[j] - bfu2f(hi));
                }
                int lbase = ((kc << 2) + quad) * 128 + col * 8;
                bf16x8 Bl0 = *(const bf16x8*)&Wlo[lbase];
                bf16x8 Bl1 = *(const bf16x8*)&Wlo[(1 << 4) * 128 + lbase];
                bf16x8 Bl2 = *(const bf16x8*)&Wlo[(2 << 4) * 128 + lbase];
                bf16x8 Bl3 = *(const bf16x8*)&Wlo[(3 << 4) * 128 + lbase];
                a0 = __builtin_amdgcn_mfma_f32_16x16x32_bf16(Ah, Bh[kc][0], a0, 0, 0, 0);
                a0 = __builtin_amdgcn_mfma_f32_16x16x32_bf16(Al, Bh[kc][0], a0, 0, 0, 0);
                a0 = __builtin_amdgcn_mfma_f32_16x16x32_bf16(Ah, Bl0,      a0, 0, 0, 0);
                a1 = __builtin_amdgcn_mfma_f32_16x16x32_bf16(Ah, Bh[kc][1], a1, 0, 0, 0);
                a1 = __builtin_amdgcn_mfma_f32_16x16x32_bf16(Al, Bh[kc][1], a1, 0, 0, 0);
                a1 = __builtin_amdgcn_mfma_f32_16x16x32_bf16(Ah, Bl1,      a1, 0, 0, 0);
                a2 = __builtin_amdgcn_mfma_f32_16x16x32_bf16(Ah, Bh[kc][2], a2, 0, 0, 0);
                a2 = __builtin_amdgcn_mfma_f32_16x16x32_bf16(Al, Bh[kc][2], a2, 0, 0, 0);
                a2 = __builtin_amdgcn_mfma_f32_16x16x32_bf16(Ah, Bl2,      a2, 0, 0, 0);
                a3 = __builtin_amdgcn_mfma_f32_16x16x32_bf16(Ah, Bh[kc][3], a3, 0, 0, 0);
                a3 = __builtin_amdgcn_mfma_f32_16x16x32_bf16(Al, Bh[kc][3], a3, 0, 0, 0);
                a3 = __builtin_amdgcn_mfma_f32_16x16x32_bf16(Ah, Bl3,      a3, 0, 0, 0);
            }
            __hip_bfloat16* hp = h1 + (size_t)(node0 + quad * 4) * HID + col;
#pragma unroll
            for (int r = 0; r < 4; ++r) {
                float dsc = dinv1[node0 + quad * 4 + r];
                hp[(size_t)r * HID + 0]  = __float2bfloat16(a0[r] * dsc);
                hp[(size_t)r * HID + 16] = __float2bfloat16(a1[r] * dsc);
                hp[(size_t)r * HID + 32] = __float2bfloat16(a2[r] * dsc);
                hp[(size_t)r * HID + 48] = __float2bfloat16(a3[r] * dsc);
            }
        }
    } else {
        const __hip_bfloat16* x = (const __hip_bfloat16*)xv_;
        const unsigned short* W1 = (const unsigned short*)W1_;
        unsigned short* Wf = Wbuf;
        for (int i = t; i < 8192; i += 256) {
            int k = i >> 6;
            int n = i & 63;
            int kc = k >> 5, kr = k & 31;
            int q = kr >> 3, j = kr & 7;
            int n0 = n >> 4, c2 = n & 15;
            Wf[((((n0 << 2) | kc) << 2) | q) * 128 + c2 * 8 + j] = W1[i];
        }
        __syncthreads();
        bf16x8 B[4][4];
#pragma unroll
        for (int n0 = 0; n0 < 4; ++n0)
#pragma unroll
            for (int kc = 0; kc < 4; ++kc)
                B[kc][n0] = *(const bf16x8*)&Wf[((((n0 << 2) | kc) << 2) | quad) * 128 + col * 8];
        int tile0 = (blockIdx.x * 4 + wave) * 2;
#pragma unroll 1
        for (int i = 0; i < 2; ++i) {
            int node0 = (tile0 + i) * 16;
            if (node0 >= NN) return;
            const __hip_bfloat16* xp = x + (size_t)(node0 + col) * FIN + quad * 8;
            f32x4 a0 = {0.f, 0.f, 0.f, 0.f}, a1 = a0, a2 = a0, a3 = a0;
#pragma unroll
            for (int kc = 0; kc < 4; ++kc) {
                bf16x8 A = *(const bf16x8*)(xp + kc * 32);
                a0 = __builtin_amdgcn_mfma_f32_16x16x32_bf16(A, B[kc][0], a0, 0, 0, 0);
                a1 = __builtin_amdgcn_mfma_f32_16x16x32_bf16(A, B[kc][1], a1, 0, 0, 0);
                a2 = __builtin_amdgcn_mfma_f32_16x16x32_bf16(A, B[kc][2], a2, 0, 0, 0);
                a3 = __builtin_amdgcn_mfma_f32_16x16x32_bf16(A, B[kc][3], a3, 0, 0, 0);
            }
            __hip_bfloat16* hp = h1 + (size_t)(node0 + quad * 4) * HID + col;
#pragma unroll
            for (int r = 0; r < 4; ++r) {
                float dsc = dinv1[node0 + quad * 4 + r];
                hp[(size_t)r * HID + 0]  = __float2bfloat16(a0[r] * dsc);
                hp[(size_t)r * HID + 16] = __float2bfloat16(a1[r] * dsc);
                hp[(size_t)r * HID + 32] = __float2bfloat16(a2[r] * dsc);
                hp[(size_t)r * HID + 48] = __float2bfloat16(a3[r] * dsc);
            }
        }
    }
}

// ---- K7: fused agg1 + gemm2 (16 lanes/node, batch 16 — benched geometry). ----
__global__ __launch_bounds__(256) void k_agg1(const int* __restrict__ rowptrN,
                                              const int2* __restrict__ epack,
                                              const float* __restrict__ dinv1,
                                              const __hip_bfloat16* __restrict__ h1,
                                              const void* __restrict__ b1,
                                              const void* __restrict__ W2,
                                              const Flags* __restrict__ fl,
                                              const float* __restrict__ dinv2,
                                              float* __restrict__ h2) {
    __shared__ float Ws[HID * COUT];     // 4 KB
    __shared__ float obuf[16][68];       // 16 node-rows, padded (bank spread)
    int t = threadIdx.x;
    int f32 = fl->f32;
    for (int i = t; i < HID * COUT; i += 256) Ws[i] = ldf(W2, i, f32);
    int nn = t >> 4;
    int n = blockIdx.x * 16 + nn;        // grid exact: 6250*16 == NN
    int l = t & 15;
    int f = l * 4;
    int wbase = t & 48;
    float dn = dinv1[n];
    int p0 = rowptrN[n], p1 = rowptrN[n + 1];
    float a0 = 0.f, a1 = 0.f, a2 = 0.f, a3 = 0.f;
    for (int p = p0; p < p1; p += 16) {
        int idx = p + l;
        int2 ev = make_int2(0, 0);           // pad: row 0 (safe), weight bits 0
        if (idx < p1) ev = epack[idx];
        float cw = __int_as_float(ev.y);
        int rj[16];
#pragma unroll
        for (int j = 0; j < 16; ++j)
            rj[j] = __shfl(ev.x, wbase + j);
        uint2 raw[16];
#pragma unroll
        for (int j = 0; j < 16; ++j)         // 16 independent 8B gathers in flight
            raw[j] = *(const uint2*)(h1 + (size_t)rj[j] * HID + f);
#pragma unroll
        for (int j = 0; j < 16; ++j) {
            float c = __shfl(cw, wbase + j);
            union { uint2 u; __hip_bfloat16 h[4]; } v; v.u = raw[j];
            a0 += c * b2f(v.h[0]);
            a1 += c * b2f(v.h[1]);
            a2 += c * b2f(v.h[2]);
            a3 += c * b2f(v.h[3]);
        }
    }
    float x0, x1, x2, x3;
    ld4bf(h1 + (size_t)n * HID + f, x0, x1, x2, x3);   // h1s[n] = dn*h1[n]
    obuf[nn][f + 0] = fmaxf(dn * (a0 + x0) + ldf(b1, f + 0, f32), 0.f);
    obuf[nn][f + 1] = fmaxf(dn * (a1 + x1) + ldf(b1, f + 1, f32), 0.f);
    obuf[nn][f + 2] = fmaxf(dn * (a2 + x2) + ldf(b1, f + 2, f32), 0.f);
    obuf[nn][f + 3] = fmaxf(dn * (a3 + x3) + ldf(b1, f + 3, f32), 0.f);
    __syncthreads();
    // fused gemm2: thread (nn, c) computes h2[n][c], k-ascending fp32 order
    int c = t & 15;
    const float* orow = obuf[nn];
    float acc = 0.f;
#pragma unroll 8
    for (int k = 0; k < HID; ++k)
        acc += orow[k] * Ws[k * COUT + c];
    h2[(size_t)n * COUT + c] = acc * dinv2[n];
}

// ---- K8: gather-aggregate layer 2 — batched 8-deep MLP gather ----
__global__ __launch_bounds__(256) void k_agg2(const int* __restrict__ rowptrN,
                                              const int2* __restrict__ epack,
                                              const float* __restrict__ dinv2,
                                              const float* __restrict__ h2,
                                              const void* __restrict__ bias2,
                                              const Flags* __restrict__ fl,
                                              const int* __restrict__ delpos,
                                              void* __restrict__ out) {
    int t = threadIdx.x;
    int n = blockIdx.x * 64 + (t >> 2);
    if (n >= NN) return;
    int l = t & 3;
    int f = l * 4;
    int wbase = t & 60;
    int f32 = fl->f32;
    int dp = *delpos;
    float dn = dinv2[n];
    int p0 = rowptrN[n], p1 = rowptrN[n + 1];
    float a0 = 0.f, a1 = 0.f, a2 = 0.f, a3 = 0.f;
    for (int p = p0; p < p1; p += 8) {
        int iA = p + l, iB = p + 4 + l;
        int2 evA = make_int2(0, 0), evB = make_int2(0, 0);
        if (iA < p1) evA = epack[iA];
        if (iB < p1) evB = epack[iB];
        float cwA = (iA == dp) ? 0.f : __int_as_float(evA.y);
        float cwB = (iB == dp) ? 0.f : __int_as_float(evB.y);
        int rj[8];
#pragma unroll
        for (int j = 0; j < 4; ++j) {
            rj[j]     = __shfl(evA.x, wbase + j);
            rj[4 + j] = __shfl(evB.x, wbase + j);
        }
        float4 hv[8];
#pragma unroll
        for (int j = 0; j < 8; ++j)          // 8 independent 16B gathers in flight
            hv[j] = *(const float4*)(h2 + (size_t)rj[j] * COUT + f);
#pragma unroll
        for (int j = 0; j < 4; ++j) {
            float cA = __shfl(cwA, wbase + j);
            float cB = __shfl(cwB, wbase + j);
            a0 += cA * hv[j].x + cB * hv[4 + j].x;
            a1 += cA * hv[j].y + cB * hv[4 + j].y;
            a2 += cA * hv[j].z + cB * hv[4 + j].z;
            a3 += cA * hv[j].w + cB * hv[4 + j].w;
        }
    }
    const float4 hn = *(const float4*)(h2 + (size_t)n * COUT + f);   // h2s[n]
    float o0 = dn * (a0 + hn.x) + ldf(bias2, f + 0, f32);
    float o1 = dn * (a1 + hn.y) + ldf(bias2, f + 1, f32);
    float o2 = dn * (a2 + hn.z) + ldf(bias2, f + 2, f32);
    float o3 = dn * (a3 + hn.w) + ldf(bias2, f + 3, f32);
    size_t idx = (size_t)n * COUT + f;
    if (f32) {
        float* op = (float*)out + idx;
        op[0] = o0; op[1] = o1; op[2] = o2; op[3] = o3;
    } else {
        union { uint2 u; __hip_bfloat16 h[4]; } pk;
        pk.h[0] = __float2bfloat16(o0); pk.h[1] = __float2bfloat16(o1);
        pk.h[2] = __float2bfloat16(o2); pk.h[3] = __float2bfloat16(o3);
        *(uint2*)((__hip_bfloat16*)out + idx) = pk.u;
    }
}

extern "C" void kernel_launch(void* const* d_in, const int* in_sizes, int n_in,
                              void* d_out, int out_size, void* d_ws, size_t ws_size,
                              hipStream_t stream) {
    const void* x  = d_in[0];
    const void* ei = d_in[1];
    const void* ew = d_in[2];
    const void* W1 = d_in[3];
    const void* b1 = d_in[4];
    const void* W2 = d_in[5];
    const void* b2 = d_in[6];

    char* wsb = (char*)d_ws;
    int*   blockhist = (int*)wsb;                      wsb += (size_t)PART_NB * NBUK * 4;
    int*   blockbase = (int*)wsb;                      wsb += (size_t)PART_NB * NBUK * 4;
    int*   buktotal  = (int*)wsb;                      wsb += (size_t)NBUK * 4;
    int*   bucketBaseArr = (int*)wsb;                  wsb += (size_t)NBUK * 4;
    float* dinv1    = (float*)wsb;                     wsb += (size_t)NN * 4;
    float* dinv2    = (float*)wsb;                     wsb += (size_t)NN * 4;
    int*   rowptrN  = (int*)wsb;                       wsb += (size_t)(NN + 1) * 4;
    wsb = (char*)(((uintptr_t)wsb + 15) & ~(uintptr_t)15);
    int2*  epack    = (int2*)wsb;                      wsb += (size_t)NE * 8;
    __hip_bfloat16* h1 = (__hip_bfloat16*)wsb;         wsb += (size_t)NN * HID * 2;
    float* h2       = (float*)wsb;                     wsb += (size_t)NN * COUT * 4;
    long long* tmp  = (long long*)wsb;                 wsb += (size_t)NE * 8;
    u64*   minkey   = (u64*)wsb;                       wsb += 8;
    Flags* fl       = (Flags*)wsb;                     wsb += 8;
    int*   delpos   = (int*)wsb;                       wsb += 8;

    k_init<<<1, 64, 0, stream>>>((const unsigned short*)x, (const int*)ei, fl,
                                 minkey, delpos, rowptrN);
    k_hist<<<PART_NB, 512, 0, stream>>>(ei, ew, fl, blockhist, minkey);
    k_scan1<<<NBUK, 256, 0, stream>>>(blockhist, buktotal);
    k_scan2<<<NBUK, 512, 0, stream>>>(blockhist, buktotal, blockbase, bucketBaseArr);
    k_scat<<<PART_NB, 512, 0, stream>>>(ei, ew, fl, blockbase, tmp);
    k_partB<<<NBUK, 512, 0, stream>>>(buktotal, bucketBaseArr, tmp, epack, rowptrN,
                                      ei, ew, fl, minkey, dinv1, dinv2, delpos);
    k_gemm1<<<(NN / 16 + 7) / 8, 256, 0, stream>>>(x, W1, fl, dinv1, h1);
    k_agg1<<<NN / 16, 256, 0, stream>>>(rowptrN, epack, dinv1, h1, b1, W2, fl,
                                        dinv2, h2);
    k_agg2<<<(NN + 63) / 64, 256, 0, stream>>>(rowptrN, epack, dinv2, h2, b2, fl,
                                               delpos, d_out);
}